// Round 3
// baseline (1413.613 us; speedup 1.0000x reference)
//
#include <hip/hip_runtime.h>
#include <hip/hip_bf16.h>

// HGCN forward (2-layer hyperbolic GCN), Poincare ball c=1.
// Inputs: x,ew,W1,b1,W2,b2 (bf16 per test label; runtime-probed fallback to fp32),
//         src,dst int32. OUTPUT: float32 (reference returns jnp.float32).
// d_out (fp32 [N,64]) doubles as the xt tangent-vector scratch; d_ws holds the
// fp32 atomic accumulator + dtype flag.
// Pipeline: probe -> layer1 -> zero -> scatter -> layer2 -> zero -> scatter -> final

#define EPSV 1e-15f
#define MAXN 0.996f   // (1 - 4e-3) / sqrt(c), c = 1

typedef unsigned short bfu;

__device__ __forceinline__ float b2f(bfu s) {
    unsigned int u = ((unsigned int)s) << 16;
    float f;
    __builtin_memcpy(&f, &u, sizeof(f));
    return f;
}

// load element idx of a float-ish input: f==0 -> bf16, f==1 -> fp32
__device__ __forceinline__ float ldx(const void* p, size_t idx, int f) {
    return f ? ((const float*)p)[idx] : b2f(((const bfu*)p)[idx]);
}

__device__ __forceinline__ float wredsum(float v) {
#pragma unroll
    for (int o = 32; o > 0; o >>= 1) v += __shfl_xor(v, o, 64);
    return v;  // butterfly: bit-identical across all 64 lanes
}

__device__ __forceinline__ float artanh_(float x) {
    x = fminf(fmaxf(x, -1.0f + 1e-7f), 1.0f - 1e-7f);
    return 0.5f * logf((1.0f + x) / (1.0f - x));
}

// mobius_matvec tail: given mx (lane's component of x_hyp @ W^T) and
// xn = clipped ||x_hyp||: matvec scale, proj, mobius_add(+hb), proj, logmap0.
__device__ __forceinline__ float mobius_tail(float mx, float xn, float hb, float y2) {
    float mxn2 = wredsum(mx * mx);
    unsigned long long nz = __ballot(mx != 0.0f);   // reference's all(mx==0) check
    float mxn = fmaxf(sqrtf(mxn2), EPSV);
    float rt = tanhf(mxn / xn * artanh_(xn));
    float mv, x2s;
    if (nz != 0ull) {
        mv = (rt / mxn) * mx;
        float mvn = fmaxf(fabsf(rt), EPSV);        // ||mv|| == |rt| analytically
        if (mvn > MAXN) mv *= MAXN / mvn;          // proj
        float cn = fminf(mvn, MAXN);
        x2s = cn * cn;
    } else {
        mv = 0.0f; x2s = 0.0f;
    }
    float xy = wredsum(mv * hb);
    float ca = 1.0f + 2.0f * xy + y2;
    float cb = 1.0f - x2s;
    float den = fmaxf(1.0f + 2.0f * xy + x2s * y2, EPSV);
    float hj = (ca * mv + cb * hb) / den;
    float hn = fmaxf(sqrtf(wredsum(hj * hj)), EPSV);
    if (hn > MAXN) { hj *= MAXN / hn; hn = MAXN; }  // proj
    return (artanh_(hn) / hn) * hj;                 // logmap0
}

// proj(expmap0(a)) -> relu(logmap0) -> proj(expmap0(.)). Returns lane component,
// *xn_out = clipped norm of the returned point.
__device__ __forceinline__ float agg_transform(float a, float* xn_out) {
    float n = fmaxf(sqrtf(wredsum(a * a)), EPSV);
    float th = tanhf(n);
    float g = th / n;
    float nh = fmaxf(th, EPSV);
    if (nh > MAXN) { g *= MAXN / nh; nh = MAXN; }
    float h = g * a;
    float t = fmaxf((artanh_(nh) / nh) * h, 0.0f);  // relu in tangent space
    float n2 = fmaxf(sqrtf(wredsum(t * t)), EPSV);
    float th2 = tanhf(n2);
    float g2 = th2 / n2;
    float nh2 = fmaxf(th2, EPSV);
    if (nh2 > MAXN) { g2 *= MAXN / nh2; nh2 = MAXN; }
    *xn_out = nh2;
    return g2 * t;
}

// hb = proj(expmap0(b)) lane component; *y2 = ||hb||^2 (wave-uniform)
__device__ __forceinline__ float bias_point(const void* bv, int lane, int f, float* y2) {
    float b = ldx(bv, lane, f);
    float bn = fmaxf(sqrtf(wredsum(b * b)), EPSV);
    float gs = tanhf(bn) / bn;
    float hbn = fmaxf(tanhf(bn), EPSV);
    if (hbn > MAXN) gs *= MAXN / hbn;
    float hb = gs * b;
    *y2 = wredsum(hb * hb);
    return hb;
}

// ---------- input-dtype probe: bf16-decode b1; fp32 data -> wild exponents ----------
__global__ void hg3_probe(const void* b1v, int* flagp) {
    int lane = threadIdx.x & 63;
    float v = b2f(((const bfu*)b1v)[lane]);
    float bad = (fabsf(v) > 1e4f || v != v) ? 1.0f : 0.0f;
    bad = wredsum(bad);
    if (lane == 0) flagp[0] = (bad > 0.0f) ? 1 : 0;
}

__global__ __launch_bounds__(256) void hg3_zero(float* __restrict__ p, int n4) {
    const float4 z = make_float4(0.f, 0.f, 0.f, 0.f);
    int stride = gridDim.x * blockDim.x;
    for (int i = blockIdx.x * blockDim.x + threadIdx.x; i < n4; i += stride)
        ((float4*)p)[i] = z;
}

// ---------- layer 1: x[N,256] -> xt[N,64] fp32 (tangent space) ----------
__global__ __launch_bounds__(256) void hg3_layer1(
    const void* __restrict__ x,
    const void* __restrict__ W1,    // [64,256] row-major
    const void* __restrict__ b1v,   // [64]
    float* __restrict__ xt, const int* __restrict__ flagp, int N)
{
    __shared__ bfu wlds[256 * 65];     // W1^T tile [k][j] (bf16 fast path)
    __shared__ float ulds[4][256];     // per-wave input row (wave-private)
    const int tid = threadIdx.x, lane = tid & 63, wv = tid >> 6;
    const int f = *flagp;

    if (!f) {
        const bfu* W = (const bfu*)W1;
        for (int idx = tid; idx < 256 * 64; idx += 256) {   // coalesced
            int j = idx >> 8, k = idx & 255;
            wlds[k * 65 + j] = W[idx];
        }
    }
    float y2;
    float hb = bias_point(b1v, lane, f, &y2);
    __syncthreads();                   // block-uniform path: no divergence hazard

    const int nw = gridDim.x * 4;
    for (int i = blockIdx.x * 4 + wv; i < N; i += nw) {
        float u0, u1, u2, u3;
        if (!f) {
            ushort4 p = *(const ushort4*)((const bfu*)x + (size_t)i * 256 + lane * 4);
            u0 = b2f(p.x); u1 = b2f(p.y); u2 = b2f(p.z); u3 = b2f(p.w);
        } else {
            float4 p = ((const float4*)((const float*)x + (size_t)i * 256))[lane];
            u0 = p.x; u1 = p.y; u2 = p.z; u3 = p.w;
        }
        // fold expmap0 + proj into scalar gamma: x_hyp = gamma * u
        float n = fmaxf(sqrtf(wredsum(u0 * u0 + u1 * u1 + u2 * u2 + u3 * u3)), EPSV);
        float th = tanhf(n);
        float gamma = th / n;
        float nh = fmaxf(th, EPSV);
        if (nh > MAXN) { gamma *= MAXN / nh; nh = MAXN; }
        float acc = 0.0f;
        if (!f) {
            *(float4*)&ulds[wv][lane * 4] = make_float4(u0, u1, u2, u3);
            const float* uu = ulds[wv];    // wave-private: no barrier needed
            for (int k = 0; k < 256; k += 4) {
                float4 u4 = *(const float4*)&uu[k];   // broadcast read
                acc = fmaf(u4.x, b2f(wlds[(k + 0) * 65 + lane]), acc);
                acc = fmaf(u4.y, b2f(wlds[(k + 1) * 65 + lane]), acc);
                acc = fmaf(u4.z, b2f(wlds[(k + 2) * 65 + lane]), acc);
                acc = fmaf(u4.w, b2f(wlds[(k + 3) * 65 + lane]), acc);
            }
        } else {                           // fp32 fallback: shfl-broadcast + W gather
            const float4* Wrow = (const float4*)((const float*)W1 + (size_t)lane * 256);
            for (int s = 0; s < 64; ++s) {
                float a0 = __shfl(u0, s), a1 = __shfl(u1, s);
                float a2 = __shfl(u2, s), a3 = __shfl(u3, s);
                float4 w4 = Wrow[s];
                acc = fmaf(a0, w4.x, fmaf(a1, w4.y, fmaf(a2, w4.z, fmaf(a3, w4.w, acc))));
            }
        }
        float o = mobius_tail(gamma * acc, nh, hb, y2);
        xt[(size_t)i * 64 + lane] = o;     // fp32
    }
}

// ---------- scatter: agg[dst] += w * xt[src], wave per edge ----------
__global__ __launch_bounds__(256) void hg3_scatter(
    const int* __restrict__ src, const int* __restrict__ dst,
    const void* __restrict__ ew,
    const float* __restrict__ xt, float* __restrict__ agg,
    const int* __restrict__ flagp, int E)
{
    const int lane = threadIdx.x & 63;
    const int f = *flagp;
    const long long wid = ((long long)blockIdx.x * blockDim.x + threadIdx.x) >> 6;
    const long long nw = ((long long)gridDim.x * blockDim.x) >> 6;
    for (long long e = wid; e < E; e += nw) {
        int s = src[e], d = dst[e];
        float w = ldx(ew, (size_t)e, f);
        float v = w * xt[(size_t)s * 64 + lane];
        atomicAdd(&agg[(size_t)d * 64 + lane], v);
    }
}

// ---------- layer 2: agg[N,64] f32 -> xt2[N,64] fp32 ----------
__global__ __launch_bounds__(256) void hg3_layer2(
    const float* __restrict__ agg,
    const void* __restrict__ W2,    // [64,64] row-major
    const void* __restrict__ b2v,   // [64]
    float* __restrict__ xt2, const int* __restrict__ flagp, int N)
{
    __shared__ bfu wlds[64 * 65];
    __shared__ float xls[4][64];       // wave-private
    const int tid = threadIdx.x, lane = tid & 63, wv = tid >> 6;
    const int f = *flagp;

    if (!f) {
        const bfu* W = (const bfu*)W2;
        for (int idx = tid; idx < 64 * 64; idx += 256) {
            int j = idx >> 6, k = idx & 63;
            wlds[k * 65 + j] = W[idx];
        }
    }
    float y2;
    float hb = bias_point(b2v, lane, f, &y2);
    __syncthreads();

    const int nw = gridDim.x * 4;
    for (int i = blockIdx.x * 4 + wv; i < N; i += nw) {
        float a = agg[(size_t)i * 64 + lane];
        float xn;
        float x2 = agg_transform(a, &xn);   // layer-2 input point
        float acc = 0.0f;
        if (!f) {
            xls[wv][lane] = x2;
            const float* xp = xls[wv];
#pragma unroll
            for (int k = 0; k < 64; k += 4) {
                acc = fmaf(xp[k + 0], b2f(wlds[(k + 0) * 65 + lane]), acc);
                acc = fmaf(xp[k + 1], b2f(wlds[(k + 1) * 65 + lane]), acc);
                acc = fmaf(xp[k + 2], b2f(wlds[(k + 2) * 65 + lane]), acc);
                acc = fmaf(xp[k + 3], b2f(wlds[(k + 3) * 65 + lane]), acc);
            }
        } else {
            const float* Wrow = (const float*)W2 + (size_t)lane * 64;
            for (int s = 0; s < 64; ++s)
                acc = fmaf(__shfl(x2, s), Wrow[s], acc);
        }
        float o = mobius_tail(acc, xn, hb, y2);
        xt2[(size_t)i * 64 + lane] = o;    // fp32
    }
}

// ---------- final: agg2 f32 -> HypAct -> fp32 out ----------
__global__ __launch_bounds__(256) void hg3_final(
    const float* __restrict__ agg, float* __restrict__ out, int N)
{
    const int lane = threadIdx.x & 63, wv = threadIdx.x >> 6;
    const int nw = gridDim.x * 4;
    for (int i = blockIdx.x * 4 + wv; i < N; i += nw) {
        float a = agg[(size_t)i * 64 + lane];
        float xn;
        float o = agg_transform(a, &xn);
        out[(size_t)i * 64 + lane] = o;    // fp32 output (reference dtype)
    }
}

extern "C" void kernel_launch(void* const* d_in, const int* in_sizes, int n_in,
                              void* d_out, int out_size, void* d_ws, size_t ws_size,
                              hipStream_t stream)
{
    const void* x  = d_in[0];
    const int* src = (const int*)d_in[1];
    const int* dst = (const int*)d_in[2];
    const void* ew = d_in[3];
    const void* W1 = d_in[4];
    const void* b1 = d_in[5];
    const void* W2 = d_in[6];
    const void* b2 = d_in[7];

    const int Dd = in_sizes[5];            // 64
    const int Ff = in_sizes[4] / Dd;       // 256
    const int N  = in_sizes[0] / Ff;       // 80000
    const int E  = in_sizes[1];            // 1280000

    float* out  = (float*)d_out;           // fp32 [N,64]
    float* xt   = (float*)d_out;           // tangent-vector scratch shares d_out
    float* agg  = (float*)d_ws;            // fp32 [N,64] accumulator
    int*   flag = (int*)(agg + (size_t)N * Dd);

    const int n4 = (N * Dd) / 4;

    hg3_probe  <<<1,     64,  0, stream>>>(b1, flag);
    hg3_layer1 <<<2048,  256, 0, stream>>>(x, W1, b1, xt, flag, N);
    hg3_zero   <<<1024,  256, 0, stream>>>(agg, n4);
    hg3_scatter<<<16384, 256, 0, stream>>>(src, dst, ew, xt, agg, flag, E);
    hg3_layer2 <<<2048,  256, 0, stream>>>(agg, W2, b2, xt, flag, N);   // in-place
    hg3_zero   <<<1024,  256, 0, stream>>>(agg, n4);
    hg3_scatter<<<16384, 256, 0, stream>>>(src, dst, ew, xt, agg, flag, E);
    hg3_final  <<<2048,  256, 0, stream>>>(agg, out, N);                // overwrites d_out last
}